// Round 4
// baseline (2496.854 us; speedup 1.0000x reference)
//
#include <hip/hip_runtime.h>
#include <hip/hip_bf16.h>

// Actor_attf_single — MI355X (gfx950)
// R4: latency/issue restructure (R3 passed at 361 µs vs ~80 µs fp32-FMA floor;
// FETCH==input size, HBM 3.6%, conflicts 0 => not memory-bound; VALUBusy=86%
// suspect (gfx94x formula), diagnosis = latency-bound k-loop weight reloads).
//   - all 4754 weight floats staged to LDS once per block (19 KB, broadcast reads)
//   - W1->W2 fused per entity; float2-paired math throughout (invites v_pk_fma_f32)
//   - branchless prefetch of next-iteration inputs across k-loop back-edge
//   - weights in natural layout (all rows contiguous; every f2 read 8B-aligned)

#define LN_EPS 1e-5f

// float offsets into LDS weight block (all even; all 16B-aligned)
enum {
  O_EN_W1 = 0,      // 4x32
  O_EN_B1 = 128,
  O_EN_W2 = 160,    // 32x16
  O_EN_B2 = 672,
  O_OA_W1 = 688,    // 4x32
  O_OA_B1 = 816,
  O_OA_W2 = 848,    // 32x16
  O_OA_B2 = 1360,
  O_GO_W1 = 1376,   // 2x32
  O_GO_B1 = 1440,
  O_GO_W2 = 1472,   // 32x16
  O_GO_B2 = 1984,
  O_OA_G  = 2000,
  O_OA_B  = 2016,
  O_GO_G  = 2032,
  O_GO_B  = 2048,
  O_A_W1  = 2064,   // 48x32
  O_A_B1  = 3600,
  O_A_W2  = 3632,   // 32x32
  O_A_B2  = 4656,
  O_A_W3  = 4688,   // 32x2
  O_A_B3  = 4752,
  W_TOTAL = 4756    // padded even
};

struct WSrc { const float* p[22]; };

__device__ __forceinline__ float2 ld2(const float* p) {
  return *reinterpret_cast<const float2*>(p);
}
__device__ __forceinline__ float2 pk_fma_s(float s, float2 b, float2 c) {
  return make_float2(fmaf(s, b.x, c.x), fmaf(s, b.y, c.y));
}
__device__ __forceinline__ float2 pk_fma(float2 a, float2 b, float2 c) {
  return make_float2(fmaf(a.x, b.x, c.x), fmaf(a.y, b.y, c.y));
}
__device__ __forceinline__ float2 pk_max0(float2 a) {
  return make_float2(fmaxf(a.x, 0.f), fmaxf(a.y, 0.f));
}

__global__ __launch_bounds__(256)
void actor_fwd(const float* __restrict__ s_input, WSrc src,
               float* __restrict__ out, int bsz) {
  __shared__ __align__(16) float sW[W_TOTAL];
  {
    const int sizes[22] = {128,32,512,16, 128,32,512,16, 64,32,512,16,
                           16,16,16,16, 1536,32,1024,32,64,2};
    const int offs[22]  = {O_EN_W1,O_EN_B1,O_EN_W2,O_EN_B2,
                           O_OA_W1,O_OA_B1,O_OA_W2,O_OA_B2,
                           O_GO_W1,O_GO_B1,O_GO_W2,O_GO_B2,
                           O_OA_G,O_OA_B,O_GO_G,O_GO_B,
                           O_A_W1,O_A_B1,O_A_W2,O_A_B2,O_A_W3,O_A_B3};
#pragma unroll 1
    for (int t = 0; t < 22; ++t) {
      const float* s = src.p[t];
      float* d = sW + offs[t];
      for (int j = threadIdx.x; j < sizes[t]; j += 256) d[j] = s[j];
    }
  }
  __syncthreads();

  const int row = blockIdx.x * blockDim.x + threadIdx.x;
  if (row >= bsz) return;
  const float* __restrict__ srow = s_input + (size_t)row * 96;

  // ---------------- self encoder: 4 -> 32 -> 16, relu ----------------
  float2 self2[8];
  {
    float2 p01 = ld2(srow + 0);
    float2 p23 = ld2(srow + 2);
    float2 h2[16];
#pragma unroll
    for (int i = 0; i < 16; ++i) h2[i] = ld2(sW + O_EN_B1 + 2*i);
#pragma unroll
    for (int i = 0; i < 16; ++i) {
      h2[i] = pk_fma_s(p01.x, ld2(sW + O_EN_W1 +  0 + 2*i), h2[i]);
      h2[i] = pk_fma_s(p01.y, ld2(sW + O_EN_W1 + 32 + 2*i), h2[i]);
      h2[i] = pk_fma_s(p23.x, ld2(sW + O_EN_W1 + 64 + 2*i), h2[i]);
      h2[i] = pk_fma_s(p23.y, ld2(sW + O_EN_W1 + 96 + 2*i), h2[i]);
      h2[i] = pk_max0(h2[i]);
    }
#pragma unroll
    for (int i = 0; i < 8; ++i) self2[i] = ld2(sW + O_EN_B2 + 2*i);
#pragma unroll
    for (int j = 0; j < 32; ++j) {
      float hj = (j & 1) ? h2[j >> 1].y : h2[j >> 1].x;
      const float* wrow = sW + O_EN_W2 + j*16;
#pragma unroll
      for (int i = 0; i < 8; ++i) self2[i] = pk_fma_s(hj, ld2(wrow + 2*i), self2[i]);
    }
#pragma unroll
    for (int i = 0; i < 8; ++i) self2[i] = pk_max0(self2[i]);
  }

  // ------- other agents: 15 x (4 -> 32 -> 16) + online-softmax attend -------
  float2 otherP[8];
  {
    float m = -3.0e38f, l = 0.f;
    float2 acc[8];
#pragma unroll
    for (int i = 0; i < 8; ++i) acc[i] = make_float2(0.f, 0.f);
    float2 a01 = ld2(srow + 4), a23 = ld2(srow + 34);
#pragma unroll 1
    for (int k = 0; k < 15; ++k) {
      const int kn = (k < 14) ? (k + 1) : 14;           // branchless prefetch
      float2 n01 = ld2(srow + 4 + 2*kn), n23 = ld2(srow + 34 + 2*kn);
      float2 h2[16];
#pragma unroll
      for (int i = 0; i < 16; ++i) h2[i] = ld2(sW + O_OA_B1 + 2*i);
#pragma unroll
      for (int i = 0; i < 16; ++i) {
        h2[i] = pk_fma_s(a01.x, ld2(sW + O_OA_W1 +  0 + 2*i), h2[i]);
        h2[i] = pk_fma_s(a01.y, ld2(sW + O_OA_W1 + 32 + 2*i), h2[i]);
        h2[i] = pk_fma_s(a23.x, ld2(sW + O_OA_W1 + 64 + 2*i), h2[i]);
        h2[i] = pk_fma_s(a23.y, ld2(sW + O_OA_W1 + 96 + 2*i), h2[i]);
        h2[i] = pk_max0(h2[i]);
      }
      float2 enc[8];
#pragma unroll
      for (int i = 0; i < 8; ++i) enc[i] = ld2(sW + O_OA_B2 + 2*i);
#pragma unroll
      for (int j = 0; j < 32; ++j) {
        float hj = (j & 1) ? h2[j >> 1].y : h2[j >> 1].x;
        const float* wrow = sW + O_OA_W2 + j*16;
#pragma unroll
        for (int i = 0; i < 8; ++i) enc[i] = pk_fma_s(hj, ld2(wrow + 2*i), enc[i]);
      }
#pragma unroll
      for (int i = 0; i < 8; ++i) enc[i] = pk_max0(enc[i]);
      float2 d2 = make_float2(0.f, 0.f);
#pragma unroll
      for (int i = 0; i < 8; ++i) d2 = pk_fma(self2[i], enc[i], d2);
      float s = (d2.x + d2.y) * 0.25f;                  // 1/sqrt(16)
      float mn    = fmaxf(m, s);
      float alpha = __expf(m - mn);                     // first iter: 0
      float w     = __expf(s - mn);
      l = fmaf(l, alpha, w);
#pragma unroll
      for (int i = 0; i < 8; ++i) {
        float2 t = make_float2(w * enc[i].x, w * enc[i].y);
        acc[i] = pk_fma_s(alpha, acc[i], t);
      }
      m = mn;
      a01 = n01; a23 = n23;
    }
    float inv = 1.f / l;
    float mu = 0.f;
#pragma unroll
    for (int i = 0; i < 8; ++i) {
      acc[i].x *= inv; acc[i].y *= inv;
      mu += acc[i].x + acc[i].y;
    }
    mu *= (1.f / 16.f);
    float var = 0.f;
#pragma unroll
    for (int i = 0; i < 8; ++i) {
      float tx = acc[i].x - mu, ty = acc[i].y - mu;
      var = fmaf(tx, tx, var); var = fmaf(ty, ty, var);
    }
    var *= (1.f / 16.f);
    float rstd = rsqrtf(var + LN_EPS);
#pragma unroll
    for (int i = 0; i < 8; ++i) {
      float2 g = ld2(sW + O_OA_G + 2*i), b = ld2(sW + O_OA_B + 2*i);
      otherP[i] = pk_max0(make_float2(fmaf((acc[i].x - mu) * rstd, g.x, b.x),
                                      fmaf((acc[i].y - mu) * rstd, g.y, b.y)));
    }
  }

  // ------- food: 16 x (2 -> 32 -> 16) + online-softmax attend -------
  float2 foodP[8];
  {
    float m = -3.0e38f, l = 0.f;
    float2 acc[8];
#pragma unroll
    for (int i = 0; i < 8; ++i) acc[i] = make_float2(0.f, 0.f);
    float2 f01 = ld2(srow + 64);
#pragma unroll 1
    for (int k = 0; k < 16; ++k) {
      const int kn = (k < 15) ? (k + 1) : 15;
      float2 n01 = ld2(srow + 64 + 2*kn);
      float2 h2[16];
#pragma unroll
      for (int i = 0; i < 16; ++i) h2[i] = ld2(sW + O_GO_B1 + 2*i);
#pragma unroll
      for (int i = 0; i < 16; ++i) {
        h2[i] = pk_fma_s(f01.x, ld2(sW + O_GO_W1 +  0 + 2*i), h2[i]);
        h2[i] = pk_fma_s(f01.y, ld2(sW + O_GO_W1 + 32 + 2*i), h2[i]);
        h2[i] = pk_max0(h2[i]);
      }
      float2 enc[8];
#pragma unroll
      for (int i = 0; i < 8; ++i) enc[i] = ld2(sW + O_GO_B2 + 2*i);
#pragma unroll
      for (int j = 0; j < 32; ++j) {
        float hj = (j & 1) ? h2[j >> 1].y : h2[j >> 1].x;
        const float* wrow = sW + O_GO_W2 + j*16;
#pragma unroll
        for (int i = 0; i < 8; ++i) enc[i] = pk_fma_s(hj, ld2(wrow + 2*i), enc[i]);
      }
#pragma unroll
      for (int i = 0; i < 8; ++i) enc[i] = pk_max0(enc[i]);
      float2 d2 = make_float2(0.f, 0.f);
#pragma unroll
      for (int i = 0; i < 8; ++i) d2 = pk_fma(self2[i], enc[i], d2);
      float s = (d2.x + d2.y) * 0.25f;
      float mn    = fmaxf(m, s);
      float alpha = __expf(m - mn);
      float w     = __expf(s - mn);
      l = fmaf(l, alpha, w);
#pragma unroll
      for (int i = 0; i < 8; ++i) {
        float2 t = make_float2(w * enc[i].x, w * enc[i].y);
        acc[i] = pk_fma_s(alpha, acc[i], t);
      }
      m = mn;
      f01 = n01;
    }
    float inv = 1.f / l;
    float mu = 0.f;
#pragma unroll
    for (int i = 0; i < 8; ++i) {
      acc[i].x *= inv; acc[i].y *= inv;
      mu += acc[i].x + acc[i].y;
    }
    mu *= (1.f / 16.f);
    float var = 0.f;
#pragma unroll
    for (int i = 0; i < 8; ++i) {
      float tx = acc[i].x - mu, ty = acc[i].y - mu;
      var = fmaf(tx, tx, var); var = fmaf(ty, ty, var);
    }
    var *= (1.f / 16.f);
    float rstd = rsqrtf(var + LN_EPS);
#pragma unroll
    for (int i = 0; i < 8; ++i) {
      float2 g = ld2(sW + O_GO_G + 2*i), b = ld2(sW + O_GO_B + 2*i);
      foodP[i] = pk_max0(make_float2(fmaf((acc[i].x - mu) * rstd, g.x, b.x),
                                     fmaf((acc[i].y - mu) * rstd, g.y, b.y)));
    }
  }

  // ------- action head: 48 -> 32 -> 32 -> 2, leaky_relu(0.01), tanh -------
  // merged order: [self, food, other]
  float2 h1[16];
#pragma unroll
  for (int i = 0; i < 16; ++i) h1[i] = ld2(sW + O_A_B1 + 2*i);
#pragma unroll
  for (int c = 0; c < 16; ++c) {
    float mc = (c & 1) ? self2[c >> 1].y : self2[c >> 1].x;
    const float* wrow = sW + O_A_W1 + c*32;
#pragma unroll
    for (int i = 0; i < 16; ++i) h1[i] = pk_fma_s(mc, ld2(wrow + 2*i), h1[i]);
  }
#pragma unroll
  for (int c = 0; c < 16; ++c) {
    float mc = (c & 1) ? foodP[c >> 1].y : foodP[c >> 1].x;
    const float* wrow = sW + O_A_W1 + (16 + c)*32;
#pragma unroll
    for (int i = 0; i < 16; ++i) h1[i] = pk_fma_s(mc, ld2(wrow + 2*i), h1[i]);
  }
#pragma unroll
  for (int c = 0; c < 16; ++c) {
    float mc = (c & 1) ? otherP[c >> 1].y : otherP[c >> 1].x;
    const float* wrow = sW + O_A_W1 + (32 + c)*32;
#pragma unroll
    for (int i = 0; i < 16; ++i) h1[i] = pk_fma_s(mc, ld2(wrow + 2*i), h1[i]);
  }
#pragma unroll
  for (int i = 0; i < 16; ++i) {
    h1[i].x = fmaxf(h1[i].x, 0.f) + 0.01f * fminf(h1[i].x, 0.f);
    h1[i].y = fmaxf(h1[i].y, 0.f) + 0.01f * fminf(h1[i].y, 0.f);
  }
  float2 h2a[16];
#pragma unroll
  for (int i = 0; i < 16; ++i) h2a[i] = ld2(sW + O_A_B2 + 2*i);
#pragma unroll
  for (int c = 0; c < 32; ++c) {
    float mc = (c & 1) ? h1[c >> 1].y : h1[c >> 1].x;
    const float* wrow = sW + O_A_W2 + c*32;
#pragma unroll
    for (int i = 0; i < 16; ++i) h2a[i] = pk_fma_s(mc, ld2(wrow + 2*i), h2a[i]);
  }
#pragma unroll
  for (int i = 0; i < 16; ++i) {
    h2a[i].x = fmaxf(h2a[i].x, 0.f) + 0.01f * fminf(h2a[i].x, 0.f);
    h2a[i].y = fmaxf(h2a[i].y, 0.f) + 0.01f * fminf(h2a[i].y, 0.f);
  }
  float2 o2 = ld2(sW + O_A_B3);
#pragma unroll
  for (int c = 0; c < 32; ++c) {
    float mc = (c & 1) ? h2a[c >> 1].y : h2a[c >> 1].x;
    o2 = pk_fma_s(mc, ld2(sW + O_A_W3 + 2*c), o2);
  }
  o2.x = tanhf(o2.x);
  o2.y = tanhf(o2.y);

  reinterpret_cast<float2*>(out)[row] = o2;
}

extern "C" void kernel_launch(void* const* d_in, const int* in_sizes, int n_in,
                              void* d_out, int out_size, void* d_ws, size_t ws_size,
                              hipStream_t stream) {
  const float* s_input = (const float*)d_in[0];
  WSrc src;
  for (int i = 0; i < 22; ++i) src.p[i] = (const float*)d_in[i + 1];

  const int bsz = in_sizes[0] / 96;          // 262144
  const int blocks = (bsz + 255) / 256;      // 1024
  actor_fwd<<<blocks, 256, 0, stream>>>(s_input, src, (float*)d_out, bsz);
}

// Round 5
// 597.605 us; speedup vs baseline: 4.1781x; 4.1781x over previous
//
#include <hip/hip_runtime.h>

// Actor_attf_single — MI355X (gfx950)
// R5: R4 post-mortem = register-spill catastrophe (VGPR 256, 6 GB scratch
// FETCH). Also LDS-broadcast weights are bandwidth-wrong (~12cyc/b128 per CU).
// This round: R3's lean skeleton + three structural fixes, register-budgeted:
//   - prep kernel packs/transposes all weights fp32 into d_ws; main kernel
//     reads them via ONE uniform base pointer + constant offsets -> s_load
//   - 2 rows per thread: every weight fetched once per 2 rows (halves the
//     per-FMA scalar-fetch overhead that stalled R3)
//   - row-pair float2 math: fma(float2, shared_scalar_weight, float2) ==
//     v_pk_fma_f32 pattern (2x fp32 rate if emitted; harmless if not)
//   - W1->W2 fused per entity (h[32] never materialized)
//   - head computed per-row to keep peak VGPR ~150 (no R4-style blowup)

#define LN_EPS 1e-5f

// float offsets into the packed weight image in d_ws
enum {
  O_EN_W1T = 0,     // [32][4]  (transposed: col j contiguous)
  O_EN_B1  = 128,
  O_EN_W2  = 160,   // [32][16] natural
  O_EN_B2  = 672,
  O_OA_W1T = 688,   // [32][4]
  O_OA_B1  = 816,
  O_OA_W2  = 848,   // [32][16]
  O_OA_B2  = 1360,
  O_GO_W1T = 1376,  // [32][2]
  O_GO_B1  = 1440,
  O_GO_W2  = 1472,  // [32][16]
  O_GO_B2  = 1984,
  O_OA_G   = 2000, O_OA_Bb = 2016, O_GO_G = 2032, O_GO_Bb = 2048,
  O_A_W1   = 2064,  // [48][32] natural
  O_A_B1   = 3600,
  O_A_W2   = 3632,  // [32][32] natural
  O_A_B2   = 4656,
  O_A_W3   = 4688,  // [32][2] natural
  O_A_B3   = 4752,
  W_TOTAL  = 4754
};

struct WSrc { const float* p[22]; };

__global__ void prep_weights(WSrc s, float* __restrict__ w) {
  const int t = threadIdx.x;
  for (int i = t; i < 128; i += 256) w[O_EN_W1T + i] = s.p[0][(i & 3) * 32 + (i >> 2)];
  for (int i = t; i < 32;  i += 256) w[O_EN_B1  + i] = s.p[1][i];
  for (int i = t; i < 512; i += 256) w[O_EN_W2  + i] = s.p[2][i];
  for (int i = t; i < 16;  i += 256) w[O_EN_B2  + i] = s.p[3][i];
  for (int i = t; i < 128; i += 256) w[O_OA_W1T + i] = s.p[4][(i & 3) * 32 + (i >> 2)];
  for (int i = t; i < 32;  i += 256) w[O_OA_B1  + i] = s.p[5][i];
  for (int i = t; i < 512; i += 256) w[O_OA_W2  + i] = s.p[6][i];
  for (int i = t; i < 16;  i += 256) w[O_OA_B2  + i] = s.p[7][i];
  for (int i = t; i < 64;  i += 256) w[O_GO_W1T + i] = s.p[8][(i & 1) * 32 + (i >> 1)];
  for (int i = t; i < 32;  i += 256) w[O_GO_B1  + i] = s.p[9][i];
  for (int i = t; i < 512; i += 256) w[O_GO_W2  + i] = s.p[10][i];
  for (int i = t; i < 16;  i += 256) w[O_GO_B2  + i] = s.p[11][i];
  for (int i = t; i < 16;  i += 256) w[O_OA_G   + i] = s.p[12][i];
  for (int i = t; i < 16;  i += 256) w[O_OA_Bb  + i] = s.p[13][i];
  for (int i = t; i < 16;  i += 256) w[O_GO_G   + i] = s.p[14][i];
  for (int i = t; i < 16;  i += 256) w[O_GO_Bb  + i] = s.p[15][i];
  for (int i = t; i < 1536; i += 256) w[O_A_W1  + i] = s.p[16][i];
  for (int i = t; i < 32;  i += 256) w[O_A_B1   + i] = s.p[17][i];
  for (int i = t; i < 1024; i += 256) w[O_A_W2  + i] = s.p[18][i];
  for (int i = t; i < 32;  i += 256) w[O_A_B2   + i] = s.p[19][i];
  for (int i = t; i < 64;  i += 256) w[O_A_W3   + i] = s.p[20][i];
  for (int i = t; i < 2;   i += 256) w[O_A_B3   + i] = s.p[21][i];
}

// c += a * s   (row-pair float2 x shared scalar weight -> v_pk_fma_f32 shape)
__device__ __forceinline__ float2 pfma_s(float2 a, float s, float2 c) {
  return make_float2(fmaf(a.x, s, c.x), fmaf(a.y, s, c.y));
}
__device__ __forceinline__ float2 max02(float2 a) {
  return make_float2(fmaxf(a.x, 0.f), fmaxf(a.y, 0.f));
}

__global__ __launch_bounds__(256)
void actor_fwd(const float* __restrict__ X, const float* __restrict__ W,
               float* __restrict__ out, int bsz) {
  const int t  = blockIdx.x * 256 + threadIdx.x;
  const int r0 = 2 * t;
  if (r0 >= bsz) return;
  const bool has2 = (r0 + 1 < bsz);
  const float* __restrict__ A = X + (size_t)r0 * 96;
  const float* __restrict__ B = has2 ? (A + 96) : A;

  // ------------- self encoder: fused 4 -> 32 -> 16, relu -------------
  float2 self2[16];
  {
    float2 p0 = make_float2(A[0], B[0]);
    float2 p1 = make_float2(A[1], B[1]);
    float2 p2 = make_float2(A[2], B[2]);
    float2 p3 = make_float2(A[3], B[3]);
#pragma unroll
    for (int d = 0; d < 16; ++d) { float b = W[O_EN_B2 + d]; self2[d] = make_float2(b, b); }
#pragma unroll
    for (int j = 0; j < 32; ++j) {
      float bj = W[O_EN_B1 + j];
      float2 h = make_float2(bj, bj);
      h = pfma_s(p0, W[O_EN_W1T + 4*j + 0], h);
      h = pfma_s(p1, W[O_EN_W1T + 4*j + 1], h);
      h = pfma_s(p2, W[O_EN_W1T + 4*j + 2], h);
      h = pfma_s(p3, W[O_EN_W1T + 4*j + 3], h);
      h = max02(h);
#pragma unroll
      for (int d = 0; d < 16; ++d) self2[d] = pfma_s(h, W[O_EN_W2 + j*16 + d], self2[d]);
    }
#pragma unroll
    for (int d = 0; d < 16; ++d) self2[d] = max02(self2[d]);
  }

  // ------- other agents: 15 x fused(4->32->16) + online softmax -------
  float2 otherP[16];
  {
    float2 m2 = make_float2(-3.0e38f, -3.0e38f), l2 = make_float2(0.f, 0.f);
    float2 acc[16];
#pragma unroll
    for (int d = 0; d < 16; ++d) acc[d] = make_float2(0.f, 0.f);
#pragma unroll 1
    for (int k = 0; k < 15; ++k) {
      float2 a0 = make_float2(A[4  + 2*k], B[4  + 2*k]);
      float2 a1 = make_float2(A[5  + 2*k], B[5  + 2*k]);
      float2 a2 = make_float2(A[34 + 2*k], B[34 + 2*k]);
      float2 a3 = make_float2(A[35 + 2*k], B[35 + 2*k]);
      float2 enc[16];
#pragma unroll
      for (int d = 0; d < 16; ++d) { float b = W[O_OA_B2 + d]; enc[d] = make_float2(b, b); }
#pragma unroll
      for (int j = 0; j < 32; ++j) {
        float bj = W[O_OA_B1 + j];
        float2 h = make_float2(bj, bj);
        h = pfma_s(a0, W[O_OA_W1T + 4*j + 0], h);
        h = pfma_s(a1, W[O_OA_W1T + 4*j + 1], h);
        h = pfma_s(a2, W[O_OA_W1T + 4*j + 2], h);
        h = pfma_s(a3, W[O_OA_W1T + 4*j + 3], h);
        h = max02(h);
#pragma unroll
        for (int d = 0; d < 16; ++d) enc[d] = pfma_s(h, W[O_OA_W2 + j*16 + d], enc[d]);
      }
      float2 dot = make_float2(0.f, 0.f);
#pragma unroll
      for (int d = 0; d < 16; ++d) {
        enc[d] = max02(enc[d]);
        dot = make_float2(fmaf(self2[d].x, enc[d].x, dot.x),
                          fmaf(self2[d].y, enc[d].y, dot.y));
      }
      float sx = dot.x * 0.25f, sy = dot.y * 0.25f;      // 1/sqrt(16)
      float mx = fmaxf(m2.x, sx), my = fmaxf(m2.y, sy);
      float ax = __expf(m2.x - mx), ay = __expf(m2.y - my);  // first iter: 0
      float wx = __expf(sx - mx),  wy = __expf(sy - my);
      l2 = make_float2(fmaf(l2.x, ax, wx), fmaf(l2.y, ay, wy));
#pragma unroll
      for (int d = 0; d < 16; ++d)
        acc[d] = make_float2(fmaf(acc[d].x, ax, wx * enc[d].x),
                             fmaf(acc[d].y, ay, wy * enc[d].y));
      m2 = make_float2(mx, my);
    }
    float2 inv = make_float2(1.f / l2.x, 1.f / l2.y);
    float2 mu = make_float2(0.f, 0.f);
#pragma unroll
    for (int d = 0; d < 16; ++d) {
      acc[d] = make_float2(acc[d].x * inv.x, acc[d].y * inv.y);
      mu = make_float2(mu.x + acc[d].x, mu.y + acc[d].y);
    }
    mu = make_float2(mu.x * (1.f/16.f), mu.y * (1.f/16.f));
    float2 var = make_float2(0.f, 0.f);
#pragma unroll
    for (int d = 0; d < 16; ++d) {
      float tx = acc[d].x - mu.x, ty = acc[d].y - mu.y;
      var = make_float2(fmaf(tx, tx, var.x), fmaf(ty, ty, var.y));
    }
    float2 rstd = make_float2(rsqrtf(var.x * (1.f/16.f) + LN_EPS),
                              rsqrtf(var.y * (1.f/16.f) + LN_EPS));
#pragma unroll
    for (int d = 0; d < 16; ++d) {
      float g = W[O_OA_G + d], bb = W[O_OA_Bb + d];
      otherP[d] = max02(make_float2(fmaf((acc[d].x - mu.x) * rstd.x, g, bb),
                                    fmaf((acc[d].y - mu.y) * rstd.y, g, bb)));
    }
  }

  // ------- food: 16 x fused(2->32->16) + online softmax -------
  float2 foodP[16];
  {
    float2 m2 = make_float2(-3.0e38f, -3.0e38f), l2 = make_float2(0.f, 0.f);
    float2 acc[16];
#pragma unroll
    for (int d = 0; d < 16; ++d) acc[d] = make_float2(0.f, 0.f);
#pragma unroll 1
    for (int k = 0; k < 16; ++k) {
      float2 f0 = make_float2(A[64 + 2*k], B[64 + 2*k]);
      float2 f1 = make_float2(A[65 + 2*k], B[65 + 2*k]);
      float2 enc[16];
#pragma unroll
      for (int d = 0; d < 16; ++d) { float b = W[O_GO_B2 + d]; enc[d] = make_float2(b, b); }
#pragma unroll
      for (int j = 0; j < 32; ++j) {
        float bj = W[O_GO_B1 + j];
        float2 h = make_float2(bj, bj);
        h = pfma_s(f0, W[O_GO_W1T + 2*j + 0], h);
        h = pfma_s(f1, W[O_GO_W1T + 2*j + 1], h);
        h = max02(h);
#pragma unroll
        for (int d = 0; d < 16; ++d) enc[d] = pfma_s(h, W[O_GO_W2 + j*16 + d], enc[d]);
      }
      float2 dot = make_float2(0.f, 0.f);
#pragma unroll
      for (int d = 0; d < 16; ++d) {
        enc[d] = max02(enc[d]);
        dot = make_float2(fmaf(self2[d].x, enc[d].x, dot.x),
                          fmaf(self2[d].y, enc[d].y, dot.y));
      }
      float sx = dot.x * 0.25f, sy = dot.y * 0.25f;
      float mx = fmaxf(m2.x, sx), my = fmaxf(m2.y, sy);
      float ax = __expf(m2.x - mx), ay = __expf(m2.y - my);
      float wx = __expf(sx - mx),  wy = __expf(sy - my);
      l2 = make_float2(fmaf(l2.x, ax, wx), fmaf(l2.y, ay, wy));
#pragma unroll
      for (int d = 0; d < 16; ++d)
        acc[d] = make_float2(fmaf(acc[d].x, ax, wx * enc[d].x),
                             fmaf(acc[d].y, ay, wy * enc[d].y));
      m2 = make_float2(mx, my);
    }
    float2 inv = make_float2(1.f / l2.x, 1.f / l2.y);
    float2 mu = make_float2(0.f, 0.f);
#pragma unroll
    for (int d = 0; d < 16; ++d) {
      acc[d] = make_float2(acc[d].x * inv.x, acc[d].y * inv.y);
      mu = make_float2(mu.x + acc[d].x, mu.y + acc[d].y);
    }
    mu = make_float2(mu.x * (1.f/16.f), mu.y * (1.f/16.f));
    float2 var = make_float2(0.f, 0.f);
#pragma unroll
    for (int d = 0; d < 16; ++d) {
      float tx = acc[d].x - mu.x, ty = acc[d].y - mu.y;
      var = make_float2(fmaf(tx, tx, var.x), fmaf(ty, ty, var.y));
    }
    float2 rstd = make_float2(rsqrtf(var.x * (1.f/16.f) + LN_EPS),
                              rsqrtf(var.y * (1.f/16.f) + LN_EPS));
#pragma unroll
    for (int d = 0; d < 16; ++d) {
      float g = W[O_GO_G + d], bb = W[O_GO_Bb + d];
      foodP[d] = max02(make_float2(fmaf((acc[d].x - mu.x) * rstd.x, g, bb),
                                   fmaf((acc[d].y - mu.y) * rstd.y, g, bb)));
    }
  }

  // ------- action head (per row to cap VGPR): 48->32->32->2 -------
  float o00, o01, o10 = 0.f, o11 = 0.f;
#pragma unroll
  for (int r = 0; r < 2; ++r) {
    float h1[32];
#pragma unroll
    for (int j = 0; j < 32; ++j) h1[j] = W[O_A_B1 + j];
#pragma unroll
    for (int c = 0; c < 16; ++c) {
      float v = r ? self2[c].y : self2[c].x;
#pragma unroll
      for (int j = 0; j < 32; ++j) h1[j] = fmaf(v, W[O_A_W1 + c*32 + j], h1[j]);
    }
#pragma unroll
    for (int c = 0; c < 16; ++c) {
      float v = r ? foodP[c].y : foodP[c].x;
#pragma unroll
      for (int j = 0; j < 32; ++j) h1[j] = fmaf(v, W[O_A_W1 + (16 + c)*32 + j], h1[j]);
    }
#pragma unroll
    for (int c = 0; c < 16; ++c) {
      float v = r ? otherP[c].y : otherP[c].x;
#pragma unroll
      for (int j = 0; j < 32; ++j) h1[j] = fmaf(v, W[O_A_W1 + (32 + c)*32 + j], h1[j]);
    }
#pragma unroll
    for (int j = 0; j < 32; ++j)
      h1[j] = fmaxf(h1[j], 0.f) + 0.01f * fminf(h1[j], 0.f);   // leaky_relu

    float h2[32];
#pragma unroll
    for (int j = 0; j < 32; ++j) h2[j] = W[O_A_B2 + j];
#pragma unroll
    for (int c = 0; c < 32; ++c) {
#pragma unroll
      for (int j = 0; j < 32; ++j) h2[j] = fmaf(h1[c], W[O_A_W2 + c*32 + j], h2[j]);
    }
#pragma unroll
    for (int j = 0; j < 32; ++j)
      h2[j] = fmaxf(h2[j], 0.f) + 0.01f * fminf(h2[j], 0.f);

    float o0 = W[O_A_B3 + 0], o1 = W[O_A_B3 + 1];
#pragma unroll
    for (int c = 0; c < 32; ++c) {
      o0 = fmaf(h2[c], W[O_A_W3 + c*2 + 0], o0);
      o1 = fmaf(h2[c], W[O_A_W3 + c*2 + 1], o1);
    }
    o0 = tanhf(o0); o1 = tanhf(o1);
    if (r == 0) { o00 = o0; o01 = o1; } else { o10 = o0; o11 = o1; }
  }

  if (has2) {
    float4 o4 = make_float4(o00, o01, o10, o11);
    *reinterpret_cast<float4*>(out + (size_t)r0 * 2) = o4;   // 16B aligned
  } else {
    out[(size_t)r0 * 2 + 0] = o00;
    out[(size_t)r0 * 2 + 1] = o01;
  }
}

extern "C" void kernel_launch(void* const* d_in, const int* in_sizes, int n_in,
                              void* d_out, int out_size, void* d_ws, size_t ws_size,
                              hipStream_t stream) {
  WSrc src;
  for (int i = 0; i < 22; ++i) src.p[i] = (const float*)d_in[i + 1];
  float* W = (float*)d_ws;   // 4754 floats = 19 KB

  prep_weights<<<1, 256, 0, stream>>>(src, W);

  const int bsz = in_sizes[0] / 96;                 // 262144
  const int threads = (bsz + 1) / 2;                // 2 rows/thread
  const int blocks = (threads + 255) / 256;         // 512
  actor_fwd<<<blocks, 256, 0, stream>>>((const float*)d_in[0], W, (float*)d_out, bsz);
}